// Round 1
// baseline (2410.618 us; speedup 1.0000x reference)
//
#include <hip/hip_runtime.h>
#include <math.h>

#define AOFF 2097152   // recon = 32*64*1024 floats, alphas follow
#define LOFF 2359296   // AOFF + 32*8*1024

__device__ __forceinline__ int clsf(int v) { return v < 2 ? v : (v > 29 ? v - 27 : 2); }

// pos[i][y][x], i<128 : soft position embedding (grid @ pos_w.T + pos_b)
__global__ void pos_kernel(const float* __restrict__ pw, const float* __restrict__ pb,
                           float* __restrict__ pos) {
    int idx = blockIdx.x * 256 + threadIdx.x;
    if (idx >= 128 * 1024) return;
    int i = idx >> 10, y = (idx >> 5) & 31, x = idx & 31;
    float gy = y * (1.f / 31.f), gx = x * (1.f / 31.f);
    pos[idx] = gy * pw[i * 4 + 0] + gx * pw[i * 4 + 1]
             + (1.f - gy) * pw[i * 4 + 2] + (1.f - gx) * pw[i * 4 + 3] + pb[i];
}

// P[o][y][x] = ct1_b[o] + convT5x5(pos) with flipped kernel (transposed conv)
__global__ void p_kernel(const float* __restrict__ pos, const float* __restrict__ w1,
                         const float* __restrict__ b1, float* __restrict__ P) {
    __shared__ float wl[128 * 25];
    int o = blockIdx.x;
    int t = threadIdx.x;
    for (int e = t; e < 3200; e += 256) {
        int i = e / 25, tap = e % 25;
        wl[e] = w1[(i * 64 + o) * 25 + tap];
    }
    __syncthreads();
    int p = blockIdx.y * 256 + t;
    int y = p >> 5, x = p & 31;
    float s = b1[o];
    for (int i = 0; i < 128; ++i) {
        const float* pr = &pos[i << 10];
        const float* wr = &wl[i * 25];
        #pragma unroll
        for (int ky = 0; ky < 5; ++ky) {
            int yy = y + ky - 2;
            if (yy < 0 || yy > 31) continue;
            #pragma unroll
            for (int kx = 0; kx < 5; ++kx) {
                int xx = x + kx - 2;
                if (xx < 0 || xx > 31) continue;
                s += pr[yy * 32 + xx] * wr[(4 - ky) * 5 + (4 - kx)];
            }
        }
    }
    P[(o << 10) + p] = s;
}

// Wsum[cls][i][o] = sum over valid taps of flipped ct1_w  (25 border classes)
__global__ void wsum_kernel(const float* __restrict__ w1, float* __restrict__ Wsum) {
    int idx = blockIdx.x * 256 + threadIdx.x;
    if (idx >= 25 * 128 * 64) return;
    int cls = idx >> 13;
    int i = (idx >> 6) & 127;
    int o = idx & 63;
    int cy = cls / 5, cx = cls % 5;
    const int klo[5] = {2, 1, 0, 0, 0}, khi[5] = {4, 4, 4, 3, 2};
    float s = 0.f;
    for (int ky = klo[cy]; ky <= khi[cy]; ++ky)
        for (int kx = klo[cx]; kx <= khi[cx]; ++kx)
            s += w1[(i * 64 + o) * 25 + (4 - ky) * 5 + (4 - kx)];
    Wsum[idx] = s;
}

// M[n][cls][o] = latent[n,:] . Wsum[cls,:,o]
__global__ void m_kernel(const float* __restrict__ latent, const float* __restrict__ Wsum,
                         float* __restrict__ M) {
    int n = blockIdx.x, cls = blockIdx.y, o = threadIdx.x;
    const float* l = &latent[n * 128];
    const float* w = &Wsum[cls * 8192 + o];
    float a0 = 0.f, a1 = 0.f;
    for (int i = 0; i < 128; i += 2) {
        a0 = fmaf(l[i], w[i * 64], a0);
        a1 = fmaf(l[i + 1], w[(i + 1) * 64], a1);
    }
    M[(n * 25 + cls) * 64 + o] = a0 + a1;
}

// convT2: feat[n][m][y][x] = relu(b2[m] + sum_{i,5x5} h * flip(ct2_w))
// h reconstructed on the fly: h[i][y][x] = relu(M[n][cls(y,x)][i] + P[i][y][x])
__global__ __launch_bounds__(1024)
void convt2_kernel(const float* __restrict__ M, const float* __restrict__ P,
                   const float* __restrict__ w2, const float* __restrict__ b2,
                   float* __restrict__ feat) {
    __shared__ float Ml[1600];
    __shared__ float h_lds[8 * 32 * 12];       // [il][x][row], stride 12
    __shared__ float wl[8 * 5 * 32 * 8];       // [il][kx][m][ky(pad8)]
    int n = blockIdx.x;
    int y0 = blockIdx.y * 8;
    int tx = threadIdx.x, ty = threadIdx.y;    // tx = x, ty = m (out ch)
    int tid = ty * 32 + tx;
    for (int e = tid; e < 1600; e += 1024) Ml[e] = M[n * 1600 + e];
    float acc[8] = {0.f, 0.f, 0.f, 0.f, 0.f, 0.f, 0.f, 0.f};
    for (int ic = 0; ic < 8; ++ic) {
        __syncthreads();
        for (int e = tid; e < 3072; e += 1024) {
            int il = e / 384;
            int rr = (e >> 5) % 12;
            int x = e & 31;
            int i = ic * 8 + il;
            int y = y0 - 2 + rr;
            float v = 0.f;
            if (y >= 0 && y < 32) {
                int cls = clsf(y) * 5 + clsf(x);
                v = fmaxf(Ml[cls * 64 + i] + P[(i << 10) + (y << 5) + x], 0.f);
            }
            h_lds[(il * 32 + x) * 12 + rr] = v;
        }
        for (int e = tid; e < 6400; e += 1024) {
            int il = e / 800;
            int kx = (e / 160) % 5;
            int m = (e / 5) % 32;
            int ky = e % 5;
            int i = ic * 8 + il;
            wl[((il * 5 + kx) * 32 + m) * 8 + ky] =
                w2[((i * 32 + m) * 5 + (4 - ky)) * 5 + (4 - kx)];
        }
        __syncthreads();
        for (int il = 0; il < 8; ++il) {
            #pragma unroll
            for (int kx = 0; kx < 5; ++kx) {
                int xx = tx + kx - 2;
                if (xx < 0 || xx > 31) continue;
                const float* cp = &h_lds[(il * 32 + xx) * 12];
                const float* wp = &wl[((il * 5 + kx) * 32 + ty) * 8];
                float col[12], wk[5];
                #pragma unroll
                for (int r = 0; r < 12; ++r) col[r] = cp[r];
                #pragma unroll
                for (int k = 0; k < 5; ++k) wk[k] = wp[k];
                #pragma unroll
                for (int ky = 0; ky < 5; ++ky)
                    #pragma unroll
                    for (int r = 0; r < 8; ++r)
                        acc[r] = fmaf(col[r + ky], wk[ky], acc[r]);
            }
        }
    }
    float b = b2[ty];
    #pragma unroll
    for (int r = 0; r < 8; ++r)
        feat[(n * 32 + ty) * 1024 + (y0 + r) * 32 + tx] = fmaxf(acc[r] + b, 0.f);
}

// generic 3x3 conv, pad 1, OIHW weights; act=1 -> silu
__global__ __launch_bounds__(1024)
void conv3_kernel(const float* __restrict__ in, const float* __restrict__ w,
                  const float* __restrict__ b, float* __restrict__ out,
                  int I, int Ot, int act) {
    __shared__ float in_lds[16 * 32 * 12];     // [il][x][row], stride 12 (10 used)
    __shared__ float wl[16 * 3 * 32 * 4];      // [il][kx][o][ky(pad4)]
    int n = blockIdx.x;
    int y0 = blockIdx.y * 8;
    int og = blockIdx.z * 32;
    int tx = threadIdx.x, ty = threadIdx.y;
    int tid = ty * 32 + tx;
    int o = og + ty;
    float acc[8] = {0.f, 0.f, 0.f, 0.f, 0.f, 0.f, 0.f, 0.f};
    int chunks = I >> 4;
    for (int ic = 0; ic < chunks; ++ic) {
        __syncthreads();
        for (int e = tid; e < 5120; e += 1024) {
            int il = e / 320;
            int rr = (e >> 5) % 10;
            int x = e & 31;
            int i = ic * 16 + il;
            int y = y0 - 1 + rr;
            float v = 0.f;
            if (y >= 0 && y < 32) v = in[(n * I + i) * 1024 + (y << 5) + x];
            in_lds[(il * 32 + x) * 12 + rr] = v;
        }
        for (int e = tid; e < 4608; e += 1024) {
            int il = e / 288;
            int kx = (e / 96) % 3;
            int oo = (e / 3) % 32;
            int ky = e % 3;
            int i = ic * 16 + il;
            wl[((il * 3 + kx) * 32 + oo) * 4 + ky] = w[((og + oo) * I + i) * 9 + ky * 3 + kx];
        }
        __syncthreads();
        for (int il = 0; il < 16; ++il) {
            #pragma unroll
            for (int kx = 0; kx < 3; ++kx) {
                int xx = tx + kx - 1;
                if (xx < 0 || xx > 31) continue;
                const float* cp = &in_lds[(il * 32 + xx) * 12];
                const float* wp = &wl[((il * 3 + kx) * 32 + ty) * 4];
                float col[10], wk[3];
                #pragma unroll
                for (int r = 0; r < 10; ++r) col[r] = cp[r];
                #pragma unroll
                for (int k = 0; k < 3; ++k) wk[k] = wp[k];
                #pragma unroll
                for (int ky = 0; ky < 3; ++ky)
                    #pragma unroll
                    for (int r = 0; r < 8; ++r)
                        acc[r] = fmaf(col[r + ky], wk[ky], acc[r]);
            }
        }
    }
    float bb = b[o];
    #pragma unroll
    for (int r = 0; r < 8; ++r) {
        float v = acc[r] + bb;
        if (act) v = v / (1.f + expf(-v));
        out[(n * Ot + o) * 1024 + (y0 + r) * 32 + tx] = v;
    }
}

// a2: 64 -> 1 channel, 3x3 pad 1
__global__ void a2_kernel(const float* __restrict__ in, const float* __restrict__ w,
                          const float* __restrict__ b, float* __restrict__ araw) {
    __shared__ float in_lds[32 * 10 * 32];
    __shared__ float wlds[576];
    int n = blockIdx.x, y0 = blockIdx.y * 8;
    int t = threadIdx.x;
    int r = t >> 5, x = t & 31;
    for (int e = t; e < 576; e += 256) wlds[e] = w[e];
    float acc = b[0];
    for (int ic = 0; ic < 2; ++ic) {
        __syncthreads();
        for (int e = t; e < 10240; e += 256) {
            int il = e / 320;
            int rr = (e >> 5) % 10;
            int xx = e & 31;
            int i = ic * 32 + il;
            int y = y0 - 1 + rr;
            in_lds[e] = (y >= 0 && y < 32) ? in[(n * 64 + i) * 1024 + (y << 5) + xx] : 0.f;
        }
        __syncthreads();
        for (int il = 0; il < 32; ++il) {
            #pragma unroll
            for (int ky = 0; ky < 3; ++ky) {
                #pragma unroll
                for (int kx = 0; kx < 3; ++kx) {
                    int xx = x + kx - 1;
                    if (xx < 0 || xx > 31) continue;
                    acc += in_lds[il * 320 + (r + ky) * 32 + xx] * wlds[(ic * 32 + il) * 9 + ky * 3 + kx];
                }
            }
        }
    }
    araw[(n << 10) + (y0 + r) * 32 + x] = acc;
}

// softmax over the 8 slots, write alphas_n into d_out[AOFF..]
__global__ void softmax_kernel(const float* __restrict__ araw, float* __restrict__ outp) {
    int idx = blockIdx.x * 256 + threadIdx.x;
    if (idx >= 32 * 1024) return;
    int bb = idx >> 10, yx = idx & 1023;
    float v[8];
    float m = -3.4e38f;
    #pragma unroll
    for (int s = 0; s < 8; ++s) { v[s] = araw[((bb * 8 + s) << 10) + yx]; m = fmaxf(m, v[s]); }
    float sum = 0.f;
    #pragma unroll
    for (int s = 0; s < 8; ++s) { v[s] = expf(v[s] - m); sum += v[s]; }
    float inv = 1.f / sum;
    #pragma unroll
    for (int s = 0; s < 8; ++s) outp[AOFF + ((bb * 8 + s) << 10) + yx] = v[s] * inv;
}

// VQ: nearest codebook entry per pixel, write q (channel-major) + per-block loss partials
__global__ void vq_kernel(const float* __restrict__ feat, const float* __restrict__ codebook,
                          float* __restrict__ qfeat, float* __restrict__ partial) {
    __shared__ float cb[4096];
    __shared__ float cn[128];
    __shared__ float wsumr[4];
    int t = threadIdx.x;
    for (int e = t; e < 4096; e += 256) cb[e] = codebook[e];
    __syncthreads();
    if (t < 128) {
        float s = 0.f;
        #pragma unroll
        for (int c = 0; c < 32; ++c) { float v = cb[t * 32 + c]; s = fmaf(v, v, s); }
        cn[t] = s;
    }
    __syncthreads();
    int idx = blockIdx.x * 256 + t;
    int n = idx >> 10, yx = idx & 1023;
    float f[32];
    #pragma unroll
    for (int c = 0; c < 32; ++c) f[c] = feat[(n * 32 + c) * 1024 + yx];
    float best = 3.4e38f; int bi = 0;
    for (int k = 0; k < 128; ++k) {
        const float* cp = &cb[k * 32];
        float d0 = 0.f, d1 = 0.f, d2 = 0.f, d3 = 0.f;
        #pragma unroll
        for (int c = 0; c < 32; c += 4) {
            d0 = fmaf(f[c], cp[c], d0);
            d1 = fmaf(f[c + 1], cp[c + 1], d1);
            d2 = fmaf(f[c + 2], cp[c + 2], d2);
            d3 = fmaf(f[c + 3], cp[c + 3], d3);
        }
        float d = cn[k] - 2.f * ((d0 + d1) + (d2 + d3));
        if (d < best) { best = d; bi = k; }
    }
    float l = 0.f;
    const float* q = &cb[bi * 32];
    #pragma unroll
    for (int c = 0; c < 32; ++c) {
        float qv = q[c];
        qfeat[(n * 32 + c) * 1024 + yx] = qv;
        float dd = qv - f[c];
        l = fmaf(dd, dd, l);
    }
    for (int off = 32; off > 0; off >>= 1) l += __shfl_down(l, off);
    int lane = t & 63, wid = t >> 6;
    if (lane == 0) wsumr[wid] = l;
    __syncthreads();
    if (t == 0) partial[blockIdx.x] = (wsumr[0] + wsumr[1]) + (wsumr[2] + wsumr[3]);
}

// recon[b][v][y][x] = sum_s alphas_n * colors  (alphas read back from d_out)
__global__ void recon_kernel(const float* __restrict__ colors, float* __restrict__ outp) {
    int idx = blockIdx.x * 256 + threadIdx.x;   // (b*64+v)*1024 + yx
    int yx = idx & 1023;
    int v = (idx >> 10) & 63;
    int bb = idx >> 16;
    float acc = 0.f;
    #pragma unroll
    for (int s = 0; s < 8; ++s) {
        float a = outp[AOFF + ((bb * 8 + s) << 10) + yx];
        float c = colors[((bb * 8 + s) * 64 + v) * 1024 + yx];
        acc = fmaf(a, c, acc);
    }
    outp[idx] = acc;
}

__global__ void loss_kernel(const float* __restrict__ partial, float* __restrict__ outp) {
    double s = 0.0;
    for (int i = 0; i < 1024; ++i) s += (double)partial[i];
    outp[LOFF] = (float)(1.25 * s / 8388608.0);
}

extern "C" void kernel_launch(void* const* d_in, const int* in_sizes, int n_in,
                              void* d_out, int out_size, void* d_ws, size_t ws_size,
                              hipStream_t stream) {
    const float* latent  = (const float*)d_in[0];
    const float* pos_w   = (const float*)d_in[1];
    const float* pos_b   = (const float*)d_in[2];
    const float* ct1_w   = (const float*)d_in[3];
    const float* ct1_b   = (const float*)d_in[4];
    const float* ct2_w   = (const float*)d_in[5];
    const float* ct2_b   = (const float*)d_in[6];
    const float* codebook= (const float*)d_in[7];
    const float* c1_w    = (const float*)d_in[8];
    const float* c1_b    = (const float*)d_in[9];
    const float* c2_w    = (const float*)d_in[10];
    const float* c2_b    = (const float*)d_in[11];
    const float* a1_w    = (const float*)d_in[12];
    const float* a1_b    = (const float*)d_in[13];
    const float* a2_w    = (const float*)d_in[14];
    const float* a2_b    = (const float*)d_in[15];
    float* out = (float*)d_out;

    float* ws     = (float*)d_ws;
    float* feat   = ws;                      // 8388608 floats
    float* qfeat  = feat + 8388608;          // 8388608
    float* colors = feat;                    // 16777216 (reuses feat+qfeat region)
    float* tmp64  = qfeat + 8388608;         // 16777216
    float* pos    = tmp64 + 16777216;        // 131072
    float* P      = pos + 131072;            // 65536
    float* Wsum   = P + 65536;               // 204800
    float* M      = Wsum + 204800;           // 409600
    float* araw   = M + 409600;              // 262144
    float* partial= araw + 262144;           // 1024

    pos_kernel<<<512, 256, 0, stream>>>(pos_w, pos_b, pos);
    p_kernel<<<dim3(64, 4), 256, 0, stream>>>(pos, ct1_w, ct1_b, P);
    wsum_kernel<<<800, 256, 0, stream>>>(ct1_w, Wsum);
    m_kernel<<<dim3(256, 25), 64, 0, stream>>>(latent, Wsum, M);
    convt2_kernel<<<dim3(256, 4), dim3(32, 32), 0, stream>>>(M, P, ct2_w, ct2_b, feat);
    // alpha head (uses feat)
    conv3_kernel<<<dim3(256, 4, 2), dim3(32, 32), 0, stream>>>(feat, a1_w, a1_b, tmp64, 32, 64, 1);
    a2_kernel<<<dim3(256, 4), 256, 0, stream>>>(tmp64, a2_w, a2_b, araw);
    softmax_kernel<<<128, 256, 0, stream>>>(araw, out);
    // VQ (uses feat)
    vq_kernel<<<1024, 256, 0, stream>>>(feat, codebook, qfeat, partial);
    // color head (uses qfeat; colors overwrites feat+qfeat which are now dead)
    conv3_kernel<<<dim3(256, 4, 2), dim3(32, 32), 0, stream>>>(qfeat, c1_w, c1_b, tmp64, 32, 64, 1);
    conv3_kernel<<<dim3(256, 4, 2), dim3(32, 32), 0, stream>>>(tmp64, c2_w, c2_b, colors, 64, 64, 0);
    recon_kernel<<<8192, 256, 0, stream>>>(colors, out);
    loss_kernel<<<1, 1, 0, stream>>>(partial, out);
}

// Round 2
// 702.669 us; speedup vs baseline: 3.4307x; 3.4307x over previous
//
#include <hip/hip_runtime.h>
#include <math.h>

#define AOFF 2097152   // recon = 32*64*1024 floats, alphas follow
#define LOFF 2359296   // AOFF + 32*8*1024

typedef __attribute__((ext_vector_type(8))) short short8;
typedef __attribute__((ext_vector_type(4))) float f32x4;
typedef __attribute__((ext_vector_type(4))) int   i32x4;

__device__ __forceinline__ int clsf(int v) { return v < 2 ? v : (v > 29 ? v - 27 : 2); }

__device__ __forceinline__ unsigned int f2bfu(float x) {
    unsigned int u = __float_as_uint(x);
    return (u + 0x7FFFu + ((u >> 16) & 1u)) >> 16;
}
__device__ __forceinline__ unsigned int cvt2(float a, float b) {
    return f2bfu(a) | (f2bfu(b) << 16);
}

// ---------------- small prologue kernels (unchanged math) ----------------

__global__ void pos_kernel(const float* __restrict__ pw, const float* __restrict__ pb,
                           float* __restrict__ pos) {
    int idx = blockIdx.x * 256 + threadIdx.x;
    if (idx >= 128 * 1024) return;
    int i = idx >> 10, y = (idx >> 5) & 31, x = idx & 31;
    float gy = y * (1.f / 31.f), gx = x * (1.f / 31.f);
    pos[idx] = gy * pw[i * 4 + 0] + gx * pw[i * 4 + 1]
             + (1.f - gy) * pw[i * 4 + 2] + (1.f - gx) * pw[i * 4 + 3] + pb[i];
}

__global__ void p_kernel(const float* __restrict__ pos, const float* __restrict__ w1,
                         const float* __restrict__ b1, float* __restrict__ P) {
    __shared__ float wl[128 * 25];
    int o = blockIdx.x;
    int t = threadIdx.x;
    for (int e = t; e < 3200; e += 256) {
        int i = e / 25, tap = e % 25;
        wl[e] = w1[(i * 64 + o) * 25 + tap];
    }
    __syncthreads();
    int p = blockIdx.y * 256 + t;
    int y = p >> 5, x = p & 31;
    float s = b1[o];
    for (int i = 0; i < 128; ++i) {
        const float* pr = &pos[i << 10];
        const float* wr = &wl[i * 25];
        #pragma unroll
        for (int ky = 0; ky < 5; ++ky) {
            int yy = y + ky - 2;
            if (yy < 0 || yy > 31) continue;
            #pragma unroll
            for (int kx = 0; kx < 5; ++kx) {
                int xx = x + kx - 2;
                if (xx < 0 || xx > 31) continue;
                s += pr[yy * 32 + xx] * wr[(4 - ky) * 5 + (4 - kx)];
            }
        }
    }
    P[(o << 10) + p] = s;
}

__global__ void wsum_kernel(const float* __restrict__ w1, float* __restrict__ Wsum) {
    int idx = blockIdx.x * 256 + threadIdx.x;
    if (idx >= 25 * 128 * 64) return;
    int cls = idx >> 13;
    int i = (idx >> 6) & 127;
    int o = idx & 63;
    int cy = cls / 5, cx = cls % 5;
    const int klo[5] = {2, 1, 0, 0, 0}, khi[5] = {4, 4, 4, 3, 2};
    float s = 0.f;
    for (int ky = klo[cy]; ky <= khi[cy]; ++ky)
        for (int kx = klo[cx]; kx <= khi[cx]; ++kx)
            s += w1[(i * 64 + o) * 25 + (4 - ky) * 5 + (4 - kx)];
    Wsum[idx] = s;
}

__global__ void m_kernel(const float* __restrict__ latent, const float* __restrict__ Wsum,
                         float* __restrict__ M) {
    int n = blockIdx.x, cls = blockIdx.y, o = threadIdx.x;
    const float* l = &latent[n * 128];
    const float* w = &Wsum[cls * 8192 + o];
    float a0 = 0.f, a1 = 0.f;
    for (int i = 0; i < 128; i += 2) {
        a0 = fmaf(l[i], w[i * 64], a0);
        a1 = fmaf(l[i + 1], w[(i + 1) * 64], a1);
    }
    M[(n * 25 + cls) * 64 + o] = a0 + a1;
}

// ---------------- weight prep: OIHW fp32 -> frag-ready bf16 ----------------
// Wt layout: [tap][ks][g][o][8j], element = W[o][i=ks*32+g*8+j] at tap.

template<int I, int O>
__global__ void prep3_kernel(const float* __restrict__ w, short* __restrict__ wt) {
    constexpr int KS = I / 32;
    int idx = blockIdx.x * 256 + threadIdx.x;
    if (idx >= 9 * KS * 4 * O * 8) return;
    int j = idx & 7;
    int fi = idx >> 3;
    int o = fi % O;
    int g = (fi / O) & 3;
    int ks = (fi / (O * 4)) % KS;
    int t = fi / (O * 4 * KS);
    int i = ks * 32 + g * 8 + j;
    int ky = t / 3, kx = t % 3;
    wt[idx] = (short)f2bfu(w[(o * I + i) * 9 + ky * 3 + kx]);
}

__global__ void prepT2_kernel(const float* __restrict__ w2, short* __restrict__ wt) {
    int idx = blockIdx.x * 256 + threadIdx.x;
    if (idx >= 25 * 2 * 4 * 32 * 8) return;
    int j = idx & 7;
    int fi = idx >> 3;
    int o = fi & 31;
    int g = (fi >> 5) & 3;
    int ks = (fi >> 7) & 1;
    int t = fi >> 8;
    int i = ks * 32 + g * 8 + j;
    int ky = t / 5, kx = t % 5;
    wt[idx] = (short)f2bfu(w2[((i * 32 + o) * 5 + (4 - ky)) * 5 + (4 - kx)]);
}

// ---------------- MFMA implicit-GEMM 3x3 conv ----------------
// block: one image n, 8 output rows; 4 waves, wave w owns rows 2w..2w+1 (64 px),
// all O out-channels (MF=O/16 M-frags). ACT: 0 none, 1 silu.

template<int I, int O, int ACT>
__global__ __launch_bounds__(256) void mconv_kernel(
        const float* __restrict__ in, const short* __restrict__ wt,
        const float* __restrict__ bias, float* __restrict__ out) {
    constexpr int XC = 34, ROWS = 10, KS = I / 32, MF = O / 16, IH = I / 2;
    constexpr int ABUF = KS * 4 * O * 8;           // shorts per tap slice
    __shared__ short tile[ROWS * XC * I];
    __shared__ short ab[2 * ABUF];
    const int n = blockIdx.x, y0 = blockIdx.y * 8;
    const int tid = threadIdx.x, w = tid >> 6, l = tid & 63;

    // stage input tile (bf16, swizzled)
    for (int e = tid; e < ROWS * XC * IH; e += 256) {
        int cx = e % XC;
        int q = e / XC;
        int ip = q % IH;
        int r = q / IH;
        int gy = y0 - 1 + r, gx = cx - 1;
        float v0 = 0.f, v1 = 0.f;
        if (gy >= 0 && gy < 32 && gx >= 0 && gx < 32) {
            const float* p = &in[(n * I + 2 * ip) * 1024 + gy * 32 + gx];
            v0 = p[0]; v1 = p[1024];
        }
        int off = ((r * XC + cx) * I + 2 * ip) * 2;
        off ^= (cx & 7) << 4;
        *(unsigned int*)((char*)tile + off) = cvt2(v0, v1);
    }
    // stage A for tap 0
    for (int e = tid; e < ABUF / 8; e += 256)
        ((i32x4*)ab)[e] = ((const i32x4*)wt)[e];
    __syncthreads();

    const int lx = l & 15, lg = l >> 4;
    const int vlin = (lx * I + lg * 8) * 2;
    f32x4 acc[MF][4];
    #pragma unroll
    for (int m = 0; m < MF; ++m)
        #pragma unroll
        for (int f = 0; f < 4; ++f)
            acc[m][f] = (f32x4){0.f, 0.f, 0.f, 0.f};

    int ky = 0, kx = 0;
    #pragma unroll 1
    for (int t = 0; t < 9; ++t) {
        if (t + 1 < 9) {
            const i32x4* src = (const i32x4*)(wt + (t + 1) * ABUF);
            i32x4* dst = (i32x4*)(ab + ((t + 1) & 1) * ABUF);
            for (int e = tid; e < ABUF / 8; e += 256) dst[e] = src[e];
        }
        const short* al = ab + (t & 1) * ABUF;
        short8 af[KS][MF];
        #pragma unroll
        for (int ks = 0; ks < KS; ++ks)
            #pragma unroll
            for (int m = 0; m < MF; ++m)
                af[ks][m] = *(const short8*)(al + ((ks * 4 + lg) * O + m * 16 + lx) * 8);
        const int vkey = ((kx + lx) & 7) << 4;
        const int tv = ((2 * w + ky) * XC + kx) * I * 2 + vlin;
        #pragma unroll
        for (int ks = 0; ks < KS; ++ks) {
            short8 bf[4];
            #pragma unroll
            for (int f = 0; f < 4; ++f) {
                const int C = (((f >> 1) * XC + (f & 1) * 16) * I) * 2 + ks * 64;
                bf[f] = *(const short8*)((char*)tile + ((tv + C) ^ vkey));
            }
            #pragma unroll
            for (int m = 0; m < MF; ++m)
                #pragma unroll
                for (int f = 0; f < 4; ++f)
                    acc[m][f] = __builtin_amdgcn_mfma_f32_16x16x32_bf16(
                        af[ks][m], bf[f], acc[m][f], 0, 0, 0);
        }
        ++kx; if (kx == 3) { kx = 0; ++ky; }
        __syncthreads();
    }

    #pragma unroll
    for (int m = 0; m < MF; ++m) {
        #pragma unroll
        for (int f = 0; f < 4; ++f) {
            int yl = 2 * w + (f >> 1), x = (f & 1) * 16 + lx;
            #pragma unroll
            for (int r = 0; r < 4; ++r) {
                int och = m * 16 + lg * 4 + r;
                float v = acc[m][f][r] + bias[och];
                if (ACT == 1) v = v / (1.f + expf(-v));
                out[(n * O + och) * 1024 + (y0 + yl) * 32 + x] = v;
            }
        }
    }
}

// ---------------- convT2 via MFMA: h reconstructed on the fly ----------------
// h[i][y][x] = relu(M[n][cls(y,x)][i] + P[i][y][x]); out = relu(conv5x5(h, w2flip)+b2)

__global__ __launch_bounds__(256) void convt2_mfma_kernel(
        const float* __restrict__ M, const float* __restrict__ P,
        const short* __restrict__ wt, const float* __restrict__ b2,
        float* __restrict__ feat) {
    constexpr int I = 64, O = 32, XC = 36, ROWS = 12, KS = 2, MF = 2;
    constexpr int ABUF = KS * 4 * O * 8;           // 2048 shorts
    __shared__ short tile[ROWS * XC * I];          // 55296 B
    __shared__ short ab[2 * ABUF];                 // 8192 B (Ml overlaid)
    float* Ml = (float*)ab;                        // 6400 B during staging only
    const int n = blockIdx.x, y0 = blockIdx.y * 8;
    const int tid = threadIdx.x, w = tid >> 6, l = tid & 63;

    for (int e = tid; e < 1600; e += 256) Ml[e] = M[n * 1600 + e];
    __syncthreads();
    for (int e = tid; e < ROWS * XC * 32; e += 256) {
        int cx = e % XC;
        int q = e / XC;
        int ip = q & 31;
        int r = q >> 5;
        int gy = y0 - 2 + r, gx = cx - 2;
        float v0 = 0.f, v1 = 0.f;
        if (gy >= 0 && gy < 32 && gx >= 0 && gx < 32) {
            int cls = clsf(gy) * 5 + clsf(gx);
            int pp = gy * 32 + gx;
            v0 = fmaxf(Ml[cls * 64 + 2 * ip]     + P[((2 * ip) << 10) + pp], 0.f);
            v1 = fmaxf(Ml[cls * 64 + 2 * ip + 1] + P[((2 * ip + 1) << 10) + pp], 0.f);
        }
        int off = ((r * XC + cx) * I + 2 * ip) * 2;
        off ^= (cx & 7) << 4;
        *(unsigned int*)((char*)tile + off) = cvt2(v0, v1);
    }
    __syncthreads();
    for (int e = tid; e < ABUF / 8; e += 256)      // A tap 0 (overwrites Ml region)
        ((i32x4*)ab)[e] = ((const i32x4*)wt)[e];
    __syncthreads();

    const int lx = l & 15, lg = l >> 4;
    const int vlin = (lx * I + lg * 8) * 2;
    f32x4 acc[MF][4];
    #pragma unroll
    for (int m = 0; m < MF; ++m)
        #pragma unroll
        for (int f = 0; f < 4; ++f)
            acc[m][f] = (f32x4){0.f, 0.f, 0.f, 0.f};

    int ky = 0, kx = 0;
    #pragma unroll 1
    for (int t = 0; t < 25; ++t) {
        if (t + 1 < 25) {
            const i32x4* src = (const i32x4*)(wt + (t + 1) * ABUF);
            i32x4* dst = (i32x4*)(ab + ((t + 1) & 1) * ABUF);
            for (int e = tid; e < ABUF / 8; e += 256) dst[e] = src[e];
        }
        const short* al = ab + (t & 1) * ABUF;
        short8 af[KS][MF];
        #pragma unroll
        for (int ks = 0; ks < KS; ++ks)
            #pragma unroll
            for (int m = 0; m < MF; ++m)
                af[ks][m] = *(const short8*)(al + ((ks * 4 + lg) * O + m * 16 + lx) * 8);
        const int vkey = ((kx + lx) & 7) << 4;
        const int tv = ((2 * w + ky) * XC + kx) * I * 2 + vlin;
        #pragma unroll
        for (int ks = 0; ks < KS; ++ks) {
            short8 bf[4];
            #pragma unroll
            for (int f = 0; f < 4; ++f) {
                const int C = (((f >> 1) * XC + (f & 1) * 16) * I) * 2 + ks * 64;
                bf[f] = *(const short8*)((char*)tile + ((tv + C) ^ vkey));
            }
            #pragma unroll
            for (int m = 0; m < MF; ++m)
                #pragma unroll
                for (int f = 0; f < 4; ++f)
                    acc[m][f] = __builtin_amdgcn_mfma_f32_16x16x32_bf16(
                        af[ks][m], bf[f], acc[m][f], 0, 0, 0);
        }
        ++kx; if (kx == 5) { kx = 0; ++ky; }
        __syncthreads();
    }

    #pragma unroll
    for (int m = 0; m < MF; ++m) {
        #pragma unroll
        for (int f = 0; f < 4; ++f) {
            int yl = 2 * w + (f >> 1), x = (f & 1) * 16 + lx;
            #pragma unroll
            for (int r = 0; r < 4; ++r) {
                int och = m * 16 + lg * 4 + r;
                float v = fmaxf(acc[m][f][r] + b2[och], 0.f);
                feat[(n * O + och) * 1024 + (y0 + yl) * 32 + x] = v;
            }
        }
    }
}

// ---------------- a2: 64 -> 1 channel, 3x3 pad 1 (VALU, small) ----------------
__global__ void a2_kernel(const float* __restrict__ in, const float* __restrict__ w,
                          const float* __restrict__ b, float* __restrict__ araw) {
    __shared__ float in_lds[32 * 10 * 32];
    __shared__ float wlds[576];
    int n = blockIdx.x, y0 = blockIdx.y * 8;
    int t = threadIdx.x;
    int r = t >> 5, x = t & 31;
    for (int e = t; e < 576; e += 256) wlds[e] = w[e];
    float acc = b[0];
    for (int ic = 0; ic < 2; ++ic) {
        __syncthreads();
        for (int e = t; e < 10240; e += 256) {
            int il = e / 320;
            int rr = (e >> 5) % 10;
            int xx = e & 31;
            int i = ic * 32 + il;
            int y = y0 - 1 + rr;
            in_lds[e] = (y >= 0 && y < 32) ? in[(n * 64 + i) * 1024 + (y << 5) + xx] : 0.f;
        }
        __syncthreads();
        for (int il = 0; il < 32; ++il) {
            #pragma unroll
            for (int ky = 0; ky < 3; ++ky) {
                #pragma unroll
                for (int kx = 0; kx < 3; ++kx) {
                    int xx = x + kx - 1;
                    if (xx < 0 || xx > 31) continue;
                    acc += in_lds[il * 320 + (r + ky) * 32 + xx] * wlds[(ic * 32 + il) * 9 + ky * 3 + kx];
                }
            }
        }
    }
    araw[(n << 10) + (y0 + r) * 32 + x] = acc;
}

__global__ void softmax_kernel(const float* __restrict__ araw, float* __restrict__ outp) {
    int idx = blockIdx.x * 256 + threadIdx.x;
    if (idx >= 32 * 1024) return;
    int bb = idx >> 10, yx = idx & 1023;
    float v[8];
    float m = -3.4e38f;
    #pragma unroll
    for (int s = 0; s < 8; ++s) { v[s] = araw[((bb * 8 + s) << 10) + yx]; m = fmaxf(m, v[s]); }
    float sum = 0.f;
    #pragma unroll
    for (int s = 0; s < 8; ++s) { v[s] = expf(v[s] - m); sum += v[s]; }
    float inv = 1.f / sum;
    #pragma unroll
    for (int s = 0; s < 8; ++s) outp[AOFF + ((bb * 8 + s) << 10) + yx] = v[s] * inv;
}

__global__ void vq_kernel(const float* __restrict__ feat, const float* __restrict__ codebook,
                          float* __restrict__ qfeat, float* __restrict__ partial) {
    __shared__ float cb[4096];
    __shared__ float cn[128];
    __shared__ float wsumr[4];
    int t = threadIdx.x;
    for (int e = t; e < 4096; e += 256) cb[e] = codebook[e];
    __syncthreads();
    if (t < 128) {
        float s = 0.f;
        #pragma unroll
        for (int c = 0; c < 32; ++c) { float v = cb[t * 32 + c]; s = fmaf(v, v, s); }
        cn[t] = s;
    }
    __syncthreads();
    int idx = blockIdx.x * 256 + t;
    int n = idx >> 10, yx = idx & 1023;
    float f[32];
    #pragma unroll
    for (int c = 0; c < 32; ++c) f[c] = feat[(n * 32 + c) * 1024 + yx];
    float best = 3.4e38f; int bi = 0;
    for (int k = 0; k < 128; ++k) {
        const float* cp = &cb[k * 32];
        float d0 = 0.f, d1 = 0.f, d2 = 0.f, d3 = 0.f;
        #pragma unroll
        for (int c = 0; c < 32; c += 4) {
            d0 = fmaf(f[c], cp[c], d0);
            d1 = fmaf(f[c + 1], cp[c + 1], d1);
            d2 = fmaf(f[c + 2], cp[c + 2], d2);
            d3 = fmaf(f[c + 3], cp[c + 3], d3);
        }
        float d = cn[k] - 2.f * ((d0 + d1) + (d2 + d3));
        if (d < best) { best = d; bi = k; }
    }
    float l = 0.f;
    const float* q = &cb[bi * 32];
    #pragma unroll
    for (int c = 0; c < 32; ++c) {
        float qv = q[c];
        qfeat[(n * 32 + c) * 1024 + yx] = qv;
        float dd = qv - f[c];
        l = fmaf(dd, dd, l);
    }
    for (int off = 32; off > 0; off >>= 1) l += __shfl_down(l, off);
    int lane = t & 63, wid = t >> 6;
    if (lane == 0) wsumr[wid] = l;
    __syncthreads();
    if (t == 0) partial[blockIdx.x] = (wsumr[0] + wsumr[1]) + (wsumr[2] + wsumr[3]);
}

__global__ void recon_kernel(const float* __restrict__ colors, float* __restrict__ outp) {
    int idx = blockIdx.x * 256 + threadIdx.x;
    int yx = idx & 1023;
    int v = (idx >> 10) & 63;
    int bb = idx >> 16;
    float acc = 0.f;
    #pragma unroll
    for (int s = 0; s < 8; ++s) {
        float a = outp[AOFF + ((bb * 8 + s) << 10) + yx];
        float c = colors[((bb * 8 + s) * 64 + v) * 1024 + yx];
        acc = fmaf(a, c, acc);
    }
    outp[idx] = acc;
}

__global__ void loss_kernel(const float* __restrict__ partial, float* __restrict__ outp) {
    __shared__ float red[4];
    int t = threadIdx.x;
    float s = 0.f;
    for (int i = t; i < 1024; i += 256) s += partial[i];
    for (int o = 32; o > 0; o >>= 1) s += __shfl_down(s, o);
    if ((t & 63) == 0) red[t >> 6] = s;
    __syncthreads();
    if (t == 0) outp[LOFF] = 1.25f * ((red[0] + red[1]) + (red[2] + red[3])) / 8388608.0f;
}

extern "C" void kernel_launch(void* const* d_in, const int* in_sizes, int n_in,
                              void* d_out, int out_size, void* d_ws, size_t ws_size,
                              hipStream_t stream) {
    const float* latent  = (const float*)d_in[0];
    const float* pos_w   = (const float*)d_in[1];
    const float* pos_b   = (const float*)d_in[2];
    const float* ct1_w   = (const float*)d_in[3];
    const float* ct1_b   = (const float*)d_in[4];
    const float* ct2_w   = (const float*)d_in[5];
    const float* ct2_b   = (const float*)d_in[6];
    const float* codebook= (const float*)d_in[7];
    const float* c1_w    = (const float*)d_in[8];
    const float* c1_b    = (const float*)d_in[9];
    const float* c2_w    = (const float*)d_in[10];
    const float* c2_b    = (const float*)d_in[11];
    const float* a1_w    = (const float*)d_in[12];
    const float* a1_b    = (const float*)d_in[13];
    const float* a2_w    = (const float*)d_in[14];
    const float* a2_b    = (const float*)d_in[15];
    float* out = (float*)d_out;

    float* ws     = (float*)d_ws;
    float* feat   = ws;                      // 8388608 floats
    float* qfeat  = feat + 8388608;          // 8388608
    float* colors = feat;                    // reuses feat+qfeat (16777216)
    float* tmp64  = qfeat + 8388608;         // 16777216
    float* pos    = tmp64 + 16777216;        // 131072
    float* P      = pos + 131072;            // 65536
    float* Wsum   = P + 65536;               // 204800
    float* M      = Wsum + 204800;           // 409600
    float* araw   = M + 409600;              // 262144
    float* partial= araw + 262144;           // 1024
    short* wtA    = (short*)(partial + 1024);    // 18432 shorts
    short* wtC1   = wtA + 18432;                 // 18432
    short* wtC2   = wtC1 + 18432;                // 36864
    short* wtT2   = wtC2 + 36864;                // 51200

    pos_kernel<<<512, 256, 0, stream>>>(pos_w, pos_b, pos);
    p_kernel<<<dim3(64, 4), 256, 0, stream>>>(pos, ct1_w, ct1_b, P);
    wsum_kernel<<<800, 256, 0, stream>>>(ct1_w, Wsum);
    m_kernel<<<dim3(256, 25), 64, 0, stream>>>(latent, Wsum, M);
    prep3_kernel<32, 64><<<72, 256, 0, stream>>>(a1_w, wtA);
    prep3_kernel<32, 64><<<72, 256, 0, stream>>>(c1_w, wtC1);
    prep3_kernel<64, 64><<<144, 256, 0, stream>>>(c2_w, wtC2);
    prepT2_kernel<<<200, 256, 0, stream>>>(ct2_w, wtT2);

    convt2_mfma_kernel<<<dim3(256, 4), 256, 0, stream>>>(M, P, wtT2, ct2_b, feat);
    // alpha head
    mconv_kernel<32, 64, 1><<<dim3(256, 4), 256, 0, stream>>>(feat, wtA, a1_b, tmp64);
    a2_kernel<<<dim3(256, 4), 256, 0, stream>>>(tmp64, a2_w, a2_b, araw);
    softmax_kernel<<<128, 256, 0, stream>>>(araw, out);
    // VQ
    vq_kernel<<<1024, 256, 0, stream>>>(feat, codebook, qfeat, partial);
    // color head
    mconv_kernel<32, 64, 1><<<dim3(256, 4), 256, 0, stream>>>(qfeat, wtC1, c1_b, tmp64);
    mconv_kernel<64, 64, 0><<<dim3(256, 4), 256, 0, stream>>>(tmp64, wtC2, c2_b, colors);
    recon_kernel<<<8192, 256, 0, stream>>>(colors, out);
    loss_kernel<<<1, 256, 0, stream>>>(partial, out);
}

// Round 3
// 447.058 us; speedup vs baseline: 5.3922x; 1.5718x over previous
//
#include <hip/hip_runtime.h>
#include <math.h>

#define AOFF 2097152   // recon = 32*64*1024 floats, alphas follow
#define LOFF 2359296   // AOFF + 32*8*1024

typedef __attribute__((ext_vector_type(8))) short short8;
typedef __attribute__((ext_vector_type(4))) float f32x4;
typedef __attribute__((ext_vector_type(4))) int   i32x4;

__device__ __forceinline__ int clsf(int v) { return v < 2 ? v : (v > 29 ? v - 27 : 2); }

__device__ __forceinline__ unsigned int f2bfu(float x) {
    unsigned int u = __float_as_uint(x);
    return (u + 0x7FFFu + ((u >> 16) & 1u)) >> 16;
}
__device__ __forceinline__ unsigned int cvt2(float a, float b) {
    return f2bfu(a) | (f2bfu(b) << 16);
}

// ---------------- P = convT1(pos) via affine decomposition ----------------
// pos[i][y][x] = A_i + B_i*(y/31) + C_i*(x/31)  (affine in y,x)
// => P[o][y][x] = b1[o] + u[cls][o] + v[cls][o]*y + w[cls][o]*x  (25 border classes)

__global__ void abc_kernel(const float* __restrict__ pw, const float* __restrict__ pb,
                           float* __restrict__ ABC) {
    int i = threadIdx.x;   // 128
    float p0 = pw[i * 4], p1 = pw[i * 4 + 1], p2 = pw[i * 4 + 2], p3 = pw[i * 4 + 3];
    ABC[i]       = p2 + p3 + pb[i];
    ABC[128 + i] = p0 - p2;
    ABC[256 + i] = p1 - p3;
}

// tapabc[tap][o][comp] = sum_i w1[(i*64+o)*25 + tap] * ABC[comp][i]
__global__ void tapdot_kernel(const float* __restrict__ w1, const float* __restrict__ ABC,
                              float* __restrict__ tapabc) {
    int idx = blockIdx.x * 256 + threadIdx.x;   // 25*64*3 = 4800
    if (idx >= 4800) return;
    int comp = idx % 3;
    int o = (idx / 3) & 63;
    int tap = idx / 192;
    const float* a = ABC + comp * 128;
    float s = 0.f;
    for (int i = 0; i < 128; ++i) s = fmaf(w1[(i * 64 + o) * 25 + tap], a[i], s);
    tapabc[idx] = s;
}

// uvw[cls][o][3]: accumulate valid flipped taps per border class
__global__ void clstab_kernel(const float* __restrict__ tapabc, const float* __restrict__ b1,
                              float* __restrict__ uvw) {
    int idx = blockIdx.x * 256 + threadIdx.x;   // 25*64 = 1600
    if (idx >= 1600) return;
    int o = idx & 63, cls = idx >> 6;
    int cy = cls / 5, cx = cls % 5;
    const int klo[5] = {2, 1, 0, 0, 0}, khi[5] = {4, 4, 4, 3, 2};
    const float inv31 = 1.f / 31.f;
    float u = b1[o], v = 0.f, w = 0.f;
    for (int ky = klo[cy]; ky <= khi[cy]; ++ky)
        for (int kx = klo[cx]; kx <= khi[cx]; ++kx) {
            int tap = (4 - ky) * 5 + (4 - kx);
            const float* t = &tapabc[(tap * 64 + o) * 3];
            u += t[0] + t[1] * (ky - 2) * inv31 + t[2] * (kx - 2) * inv31;
            v += t[1] * inv31;
            w += t[2] * inv31;
        }
    uvw[idx * 3] = u; uvw[idx * 3 + 1] = v; uvw[idx * 3 + 2] = w;
}

__global__ void pfill_kernel(const float* __restrict__ uvw, float* __restrict__ P) {
    int idx = blockIdx.x * 256 + threadIdx.x;   // 64*1024
    int o = idx >> 10, y = (idx >> 5) & 31, x = idx & 31;
    int cls = clsf(y) * 5 + clsf(x);
    const float* t = &uvw[(cls * 64 + o) * 3];
    P[idx] = t[0] + t[1] * y + t[2] * x;
}

// ---------------- latent collapse of convT1 (unchanged) ----------------

__global__ void wsum_kernel(const float* __restrict__ w1, float* __restrict__ Wsum) {
    int idx = blockIdx.x * 256 + threadIdx.x;
    if (idx >= 25 * 128 * 64) return;
    int cls = idx >> 13;
    int i = (idx >> 6) & 127;
    int o = idx & 63;
    int cy = cls / 5, cx = cls % 5;
    const int klo[5] = {2, 1, 0, 0, 0}, khi[5] = {4, 4, 4, 3, 2};
    float s = 0.f;
    for (int ky = klo[cy]; ky <= khi[cy]; ++ky)
        for (int kx = klo[cx]; kx <= khi[cx]; ++kx)
            s += w1[(i * 64 + o) * 25 + (4 - ky) * 5 + (4 - kx)];
    Wsum[idx] = s;
}

__global__ void m_kernel(const float* __restrict__ latent, const float* __restrict__ Wsum,
                         float* __restrict__ M) {
    int n = blockIdx.x, cls = blockIdx.y, o = threadIdx.x;
    const float* l = &latent[n * 128];
    const float* w = &Wsum[cls * 8192 + o];
    float a0 = 0.f, a1 = 0.f;
    for (int i = 0; i < 128; i += 2) {
        a0 = fmaf(l[i], w[i * 64], a0);
        a1 = fmaf(l[i + 1], w[(i + 1) * 64], a1);
    }
    M[(n * 25 + cls) * 64 + o] = a0 + a1;
}

// ---------------- weight prep: OIHW fp32 -> frag-ready bf16 ----------------

template<int I, int O>
__global__ void prep3_kernel(const float* __restrict__ w, short* __restrict__ wt) {
    constexpr int KS = I / 32;
    int idx = blockIdx.x * 256 + threadIdx.x;
    if (idx >= 9 * KS * 4 * O * 8) return;
    int j = idx & 7;
    int fi = idx >> 3;
    int o = fi % O;
    int g = (fi / O) & 3;
    int ks = (fi / (O * 4)) % KS;
    int t = fi / (O * 4 * KS);
    int i = ks * 32 + g * 8 + j;
    int ky = t / 3, kx = t % 3;
    wt[idx] = (short)f2bfu(w[(o * I + i) * 9 + ky * 3 + kx]);
}

__global__ void prepT2_kernel(const float* __restrict__ w2, short* __restrict__ wt) {
    int idx = blockIdx.x * 256 + threadIdx.x;
    if (idx >= 25 * 2 * 4 * 32 * 8) return;
    int j = idx & 7;
    int fi = idx >> 3;
    int o = fi & 31;
    int g = (fi >> 5) & 3;
    int ks = (fi >> 7) & 1;
    int t = fi >> 8;
    int i = ks * 32 + g * 8 + j;
    int ky = t / 5, kx = t % 5;
    wt[idx] = (short)f2bfu(w2[((i * 32 + o) * 5 + (4 - ky)) * 5 + (4 - kx)]);
}

// ---------------- MFMA implicit-GEMM 3x3 conv ----------------

template<int I, int O, int ACT>
__global__ __launch_bounds__(256) void mconv_kernel(
        const float* __restrict__ in, const short* __restrict__ wt,
        const float* __restrict__ bias, float* __restrict__ out) {
    constexpr int XC = 34, ROWS = 10, KS = I / 32, MF = O / 16, IH = I / 2;
    constexpr int ABUF = KS * 4 * O * 8;
    __shared__ short tile[ROWS * XC * I];
    __shared__ short ab[2 * ABUF];
    const int n = blockIdx.x, y0 = blockIdx.y * 8;
    const int tid = threadIdx.x, w = tid >> 6, l = tid & 63;

    for (int e = tid; e < ROWS * XC * IH; e += 256) {
        int cx = e % XC;
        int q = e / XC;
        int ip = q % IH;
        int r = q / IH;
        int gy = y0 - 1 + r, gx = cx - 1;
        float v0 = 0.f, v1 = 0.f;
        if (gy >= 0 && gy < 32 && gx >= 0 && gx < 32) {
            const float* p = &in[(n * I + 2 * ip) * 1024 + gy * 32 + gx];
            v0 = p[0]; v1 = p[1024];
        }
        int off = ((r * XC + cx) * I + 2 * ip) * 2;
        off ^= (cx & 7) << 4;
        *(unsigned int*)((char*)tile + off) = cvt2(v0, v1);
    }
    for (int e = tid; e < ABUF / 8; e += 256)
        ((i32x4*)ab)[e] = ((const i32x4*)wt)[e];
    __syncthreads();

    const int lx = l & 15, lg = l >> 4;
    const int vlin = (lx * I + lg * 8) * 2;
    f32x4 acc[MF][4];
    #pragma unroll
    for (int m = 0; m < MF; ++m)
        #pragma unroll
        for (int f = 0; f < 4; ++f)
            acc[m][f] = (f32x4){0.f, 0.f, 0.f, 0.f};

    int ky = 0, kx = 0;
    #pragma unroll 1
    for (int t = 0; t < 9; ++t) {
        if (t + 1 < 9) {
            const i32x4* src = (const i32x4*)(wt + (t + 1) * ABUF);
            i32x4* dst = (i32x4*)(ab + ((t + 1) & 1) * ABUF);
            for (int e = tid; e < ABUF / 8; e += 256) dst[e] = src[e];
        }
        const short* al = ab + (t & 1) * ABUF;
        short8 af[KS][MF];
        #pragma unroll
        for (int ks = 0; ks < KS; ++ks)
            #pragma unroll
            for (int m = 0; m < MF; ++m)
                af[ks][m] = *(const short8*)(al + ((ks * 4 + lg) * O + m * 16 + lx) * 8);
        const int vkey = ((kx + lx) & 7) << 4;
        const int tv = ((2 * w + ky) * XC + kx) * I * 2 + vlin;
        #pragma unroll
        for (int ks = 0; ks < KS; ++ks) {
            short8 bf[4];
            #pragma unroll
            for (int f = 0; f < 4; ++f) {
                const int C = (((f >> 1) * XC + (f & 1) * 16) * I) * 2 + ks * 64;
                bf[f] = *(const short8*)((char*)tile + ((tv + C) ^ vkey));
            }
            #pragma unroll
            for (int m = 0; m < MF; ++m)
                #pragma unroll
                for (int f = 0; f < 4; ++f)
                    acc[m][f] = __builtin_amdgcn_mfma_f32_16x16x32_bf16(
                        af[ks][m], bf[f], acc[m][f], 0, 0, 0);
        }
        ++kx; if (kx == 3) { kx = 0; ++ky; }
        __syncthreads();
    }

    #pragma unroll
    for (int m = 0; m < MF; ++m) {
        #pragma unroll
        for (int f = 0; f < 4; ++f) {
            int yl = 2 * w + (f >> 1), x = (f & 1) * 16 + lx;
            #pragma unroll
            for (int r = 0; r < 4; ++r) {
                int och = m * 16 + lg * 4 + r;
                float v = acc[m][f][r] + bias[och];
                if (ACT == 1) v = v / (1.f + expf(-v));
                out[(n * O + och) * 1024 + (y0 + yl) * 32 + x] = v;
            }
        }
    }
}

// ---------------- convT2 via MFMA ----------------

__global__ __launch_bounds__(256) void convt2_mfma_kernel(
        const float* __restrict__ M, const float* __restrict__ P,
        const short* __restrict__ wt, const float* __restrict__ b2,
        float* __restrict__ feat) {
    constexpr int I = 64, O = 32, XC = 36, ROWS = 12, KS = 2, MF = 2;
    constexpr int ABUF = KS * 4 * O * 8;
    __shared__ short tile[ROWS * XC * I];
    __shared__ short ab[2 * ABUF];
    float* Ml = (float*)ab;
    const int n = blockIdx.x, y0 = blockIdx.y * 8;
    const int tid = threadIdx.x, w = tid >> 6, l = tid & 63;

    for (int e = tid; e < 1600; e += 256) Ml[e] = M[n * 1600 + e];
    __syncthreads();
    for (int e = tid; e < ROWS * XC * 32; e += 256) {
        int cx = e % XC;
        int q = e / XC;
        int ip = q & 31;
        int r = q >> 5;
        int gy = y0 - 2 + r, gx = cx - 2;
        float v0 = 0.f, v1 = 0.f;
        if (gy >= 0 && gy < 32 && gx >= 0 && gx < 32) {
            int cls = clsf(gy) * 5 + clsf(gx);
            int pp = gy * 32 + gx;
            v0 = fmaxf(Ml[cls * 64 + 2 * ip]     + P[((2 * ip) << 10) + pp], 0.f);
            v1 = fmaxf(Ml[cls * 64 + 2 * ip + 1] + P[((2 * ip + 1) << 10) + pp], 0.f);
        }
        int off = ((r * XC + cx) * I + 2 * ip) * 2;
        off ^= (cx & 7) << 4;
        *(unsigned int*)((char*)tile + off) = cvt2(v0, v1);
    }
    __syncthreads();
    for (int e = tid; e < ABUF / 8; e += 256)
        ((i32x4*)ab)[e] = ((const i32x4*)wt)[e];
    __syncthreads();

    const int lx = l & 15, lg = l >> 4;
    const int vlin = (lx * I + lg * 8) * 2;
    f32x4 acc[MF][4];
    #pragma unroll
    for (int m = 0; m < MF; ++m)
        #pragma unroll
        for (int f = 0; f < 4; ++f)
            acc[m][f] = (f32x4){0.f, 0.f, 0.f, 0.f};

    int ky = 0, kx = 0;
    #pragma unroll 1
    for (int t = 0; t < 25; ++t) {
        if (t + 1 < 25) {
            const i32x4* src = (const i32x4*)(wt + (t + 1) * ABUF);
            i32x4* dst = (i32x4*)(ab + ((t + 1) & 1) * ABUF);
            for (int e = tid; e < ABUF / 8; e += 256) dst[e] = src[e];
        }
        const short* al = ab + (t & 1) * ABUF;
        short8 af[KS][MF];
        #pragma unroll
        for (int ks = 0; ks < KS; ++ks)
            #pragma unroll
            for (int m = 0; m < MF; ++m)
                af[ks][m] = *(const short8*)(al + ((ks * 4 + lg) * O + m * 16 + lx) * 8);
        const int vkey = ((kx + lx) & 7) << 4;
        const int tv = ((2 * w + ky) * XC + kx) * I * 2 + vlin;
        #pragma unroll
        for (int ks = 0; ks < KS; ++ks) {
            short8 bf[4];
            #pragma unroll
            for (int f = 0; f < 4; ++f) {
                const int C = (((f >> 1) * XC + (f & 1) * 16) * I) * 2 + ks * 64;
                bf[f] = *(const short8*)((char*)tile + ((tv + C) ^ vkey));
            }
            #pragma unroll
            for (int m = 0; m < MF; ++m)
                #pragma unroll
                for (int f = 0; f < 4; ++f)
                    acc[m][f] = __builtin_amdgcn_mfma_f32_16x16x32_bf16(
                        af[ks][m], bf[f], acc[m][f], 0, 0, 0);
        }
        ++kx; if (kx == 5) { kx = 0; ++ky; }
        __syncthreads();
    }

    #pragma unroll
    for (int m = 0; m < MF; ++m) {
        #pragma unroll
        for (int f = 0; f < 4; ++f) {
            int yl = 2 * w + (f >> 1), x = (f & 1) * 16 + lx;
            #pragma unroll
            for (int r = 0; r < 4; ++r) {
                int och = m * 16 + lg * 4 + r;
                float v = fmaxf(acc[m][f][r] + b2[och], 0.f);
                feat[(n * O + och) * 1024 + (y0 + yl) * 32 + x] = v;
            }
        }
    }
}

// ---------------- a2: 64 -> 1 channel, 3x3 pad 1 ----------------
__global__ void a2_kernel(const float* __restrict__ in, const float* __restrict__ w,
                          const float* __restrict__ b, float* __restrict__ araw) {
    __shared__ float in_lds[32 * 10 * 32];
    __shared__ float wlds[576];
    int n = blockIdx.x, y0 = blockIdx.y * 8;
    int t = threadIdx.x;
    int r = t >> 5, x = t & 31;
    for (int e = t; e < 576; e += 256) wlds[e] = w[e];
    float acc = b[0];
    for (int ic = 0; ic < 2; ++ic) {
        __syncthreads();
        for (int e = t; e < 10240; e += 256) {
            int il = e / 320;
            int rr = (e >> 5) % 10;
            int xx = e & 31;
            int i = ic * 32 + il;
            int y = y0 - 1 + rr;
            in_lds[e] = (y >= 0 && y < 32) ? in[(n * 64 + i) * 1024 + (y << 5) + xx] : 0.f;
        }
        __syncthreads();
        for (int il = 0; il < 32; ++il) {
            #pragma unroll
            for (int ky = 0; ky < 3; ++ky) {
                #pragma unroll
                for (int kx = 0; kx < 3; ++kx) {
                    int xx = x + kx - 1;
                    if (xx < 0 || xx > 31) continue;
                    acc += in_lds[il * 320 + (r + ky) * 32 + xx] * wlds[(ic * 32 + il) * 9 + ky * 3 + kx];
                }
            }
        }
    }
    araw[(n << 10) + (y0 + r) * 32 + x] = acc;
}

__global__ void softmax_kernel(const float* __restrict__ araw, float* __restrict__ outp) {
    int idx = blockIdx.x * 256 + threadIdx.x;
    if (idx >= 32 * 1024) return;
    int bb = idx >> 10, yx = idx & 1023;
    float v[8];
    float m = -3.4e38f;
    #pragma unroll
    for (int s = 0; s < 8; ++s) { v[s] = araw[((bb * 8 + s) << 10) + yx]; m = fmaxf(m, v[s]); }
    float sum = 0.f;
    #pragma unroll
    for (int s = 0; s < 8; ++s) { v[s] = expf(v[s] - m); sum += v[s]; }
    float inv = 1.f / sum;
    #pragma unroll
    for (int s = 0; s < 8; ++s) outp[AOFF + ((bb * 8 + s) << 10) + yx] = v[s] * inv;
}

__global__ void vq_kernel(const float* __restrict__ feat, const float* __restrict__ codebook,
                          float* __restrict__ qfeat, float* __restrict__ partial) {
    __shared__ float cb[4096];
    __shared__ float cn[128];
    __shared__ float wsumr[4];
    int t = threadIdx.x;
    for (int e = t; e < 4096; e += 256) cb[e] = codebook[e];
    __syncthreads();
    if (t < 128) {
        float s = 0.f;
        #pragma unroll
        for (int c = 0; c < 32; ++c) { float v = cb[t * 32 + c]; s = fmaf(v, v, s); }
        cn[t] = s;
    }
    __syncthreads();
    int idx = blockIdx.x * 256 + t;
    int n = idx >> 10, yx = idx & 1023;
    float f[32];
    #pragma unroll
    for (int c = 0; c < 32; ++c) f[c] = feat[(n * 32 + c) * 1024 + yx];
    float best = 3.4e38f; int bi = 0;
    for (int k = 0; k < 128; ++k) {
        const float* cp = &cb[k * 32];
        float d0 = 0.f, d1 = 0.f, d2 = 0.f, d3 = 0.f;
        #pragma unroll
        for (int c = 0; c < 32; c += 4) {
            d0 = fmaf(f[c], cp[c], d0);
            d1 = fmaf(f[c + 1], cp[c + 1], d1);
            d2 = fmaf(f[c + 2], cp[c + 2], d2);
            d3 = fmaf(f[c + 3], cp[c + 3], d3);
        }
        float d = cn[k] - 2.f * ((d0 + d1) + (d2 + d3));
        if (d < best) { best = d; bi = k; }
    }
    float l = 0.f;
    const float* q = &cb[bi * 32];
    #pragma unroll
    for (int c = 0; c < 32; ++c) {
        float qv = q[c];
        qfeat[(n * 32 + c) * 1024 + yx] = qv;
        float dd = qv - f[c];
        l = fmaf(dd, dd, l);
    }
    for (int off = 32; off > 0; off >>= 1) l += __shfl_down(l, off);
    int lane = t & 63, wid = t >> 6;
    if (lane == 0) wsumr[wid] = l;
    __syncthreads();
    if (t == 0) partial[blockIdx.x] = (wsumr[0] + wsumr[1]) + (wsumr[2] + wsumr[3]);
}

__global__ void recon_kernel(const float* __restrict__ colors, float* __restrict__ outp) {
    int idx = blockIdx.x * 256 + threadIdx.x;
    int yx = idx & 1023;
    int v = (idx >> 10) & 63;
    int bb = idx >> 16;
    float acc = 0.f;
    #pragma unroll
    for (int s = 0; s < 8; ++s) {
        float a = outp[AOFF + ((bb * 8 + s) << 10) + yx];
        float c = colors[((bb * 8 + s) * 64 + v) * 1024 + yx];
        acc = fmaf(a, c, acc);
    }
    outp[idx] = acc;
}

__global__ void loss_kernel(const float* __restrict__ partial, float* __restrict__ outp) {
    __shared__ float red[4];
    int t = threadIdx.x;
    float s = 0.f;
    for (int i = t; i < 1024; i += 256) s += partial[i];
    for (int o = 32; o > 0; o >>= 1) s += __shfl_down(s, o);
    if ((t & 63) == 0) red[t >> 6] = s;
    __syncthreads();
    if (t == 0) outp[LOFF] = 1.25f * ((red[0] + red[1]) + (red[2] + red[3])) / 8388608.0f;
}

extern "C" void kernel_launch(void* const* d_in, const int* in_sizes, int n_in,
                              void* d_out, int out_size, void* d_ws, size_t ws_size,
                              hipStream_t stream) {
    const float* latent  = (const float*)d_in[0];
    const float* pos_w   = (const float*)d_in[1];
    const float* pos_b   = (const float*)d_in[2];
    const float* ct1_w   = (const float*)d_in[3];
    const float* ct1_b   = (const float*)d_in[4];
    const float* ct2_w   = (const float*)d_in[5];
    const float* ct2_b   = (const float*)d_in[6];
    const float* codebook= (const float*)d_in[7];
    const float* c1_w    = (const float*)d_in[8];
    const float* c1_b    = (const float*)d_in[9];
    const float* c2_w    = (const float*)d_in[10];
    const float* c2_b    = (const float*)d_in[11];
    const float* a1_w    = (const float*)d_in[12];
    const float* a1_b    = (const float*)d_in[13];
    const float* a2_w    = (const float*)d_in[14];
    const float* a2_b    = (const float*)d_in[15];
    float* out = (float*)d_out;

    float* ws     = (float*)d_ws;
    float* feat   = ws;                      // 8388608 floats
    float* qfeat  = feat + 8388608;          // 8388608
    float* colors = feat;                    // reuses feat+qfeat (16777216)
    float* tmp64  = qfeat + 8388608;         // 16777216
    float* ABC    = tmp64 + 16777216;        // 384
    float* tapabc = ABC + 384;               // 4800
    float* uvw    = tapabc + 4800;           // 4800
    float* P      = uvw + 4800;              // 65536
    float* Wsum   = P + 65536;               // 204800
    float* M      = Wsum + 204800;           // 409600
    float* araw   = M + 409600;              // 262144
    float* partial= araw + 262144;           // 1024
    short* wtA    = (short*)(partial + 1024);    // 18432 shorts
    short* wtC1   = wtA + 18432;                 // 18432
    short* wtC2   = wtC1 + 18432;                // 36864
    short* wtT2   = wtC2 + 36864;                // 51200

    abc_kernel<<<1, 128, 0, stream>>>(pos_w, pos_b, ABC);
    tapdot_kernel<<<19, 256, 0, stream>>>(ct1_w, ABC, tapabc);
    clstab_kernel<<<7, 256, 0, stream>>>(tapabc, ct1_b, uvw);
    pfill_kernel<<<256, 256, 0, stream>>>(uvw, P);
    wsum_kernel<<<800, 256, 0, stream>>>(ct1_w, Wsum);
    m_kernel<<<dim3(256, 25), 64, 0, stream>>>(latent, Wsum, M);
    prep3_kernel<32, 64><<<72, 256, 0, stream>>>(a1_w, wtA);
    prep3_kernel<32, 64><<<72, 256, 0, stream>>>(c1_w, wtC1);
    prep3_kernel<64, 64><<<144, 256, 0, stream>>>(c2_w, wtC2);
    prepT2_kernel<<<200, 256, 0, stream>>>(ct2_w, wtT2);

    convt2_mfma_kernel<<<dim3(256, 4), 256, 0, stream>>>(M, P, wtT2, ct2_b, feat);
    // alpha head
    mconv_kernel<32, 64, 1><<<dim3(256, 4), 256, 0, stream>>>(feat, wtA, a1_b, tmp64);
    a2_kernel<<<dim3(256, 4), 256, 0, stream>>>(tmp64, a2_w, a2_b, araw);
    softmax_kernel<<<128, 256, 0, stream>>>(araw, out);
    // VQ
    vq_kernel<<<1024, 256, 0, stream>>>(feat, codebook, qfeat, partial);
    // color head
    mconv_kernel<32, 64, 1><<<dim3(256, 4), 256, 0, stream>>>(qfeat, wtC1, c1_b, tmp64);
    mconv_kernel<64, 64, 0><<<dim3(256, 4), 256, 0, stream>>>(tmp64, wtC2, c2_b, colors);
    recon_kernel<<<8192, 256, 0, stream>>>(colors, out);
    loss_kernel<<<1, 256, 0, stream>>>(partial, out);
}

// Round 4
// 367.406 us; speedup vs baseline: 6.5612x; 1.2168x over previous
//
#include <hip/hip_runtime.h>
#include <math.h>

#define AOFF 2097152   // recon = 32*64*1024 floats, alphas follow
#define LOFF 2359296   // AOFF + 32*8*1024

typedef __attribute__((ext_vector_type(8))) short short8;
typedef __attribute__((ext_vector_type(4))) float f32x4;
typedef __attribute__((ext_vector_type(4))) int   i32x4;

__device__ __forceinline__ int clsf(int v) { return v < 2 ? v : (v > 29 ? v - 27 : 2); }

__device__ __forceinline__ unsigned int f2bfu(float x) {
    unsigned int u = __float_as_uint(x);
    return (u + 0x7FFFu + ((u >> 16) & 1u)) >> 16;
}
__device__ __forceinline__ unsigned int cvt2(float a, float b) {
    return f2bfu(a) | (f2bfu(b) << 16);
}
__device__ __forceinline__ float bf2f(unsigned short u) {
    return __uint_as_float(((unsigned int)u) << 16);
}

// ---------------- P = convT1(pos) via affine decomposition ----------------

__global__ void abc_kernel(const float* __restrict__ pw, const float* __restrict__ pb,
                           float* __restrict__ ABC) {
    int i = threadIdx.x;   // 128
    float p0 = pw[i * 4], p1 = pw[i * 4 + 1], p2 = pw[i * 4 + 2], p3 = pw[i * 4 + 3];
    ABC[i]       = p2 + p3 + pb[i];
    ABC[128 + i] = p0 - p2;
    ABC[256 + i] = p1 - p3;
}

__global__ void tapdot_kernel(const float* __restrict__ w1, const float* __restrict__ ABC,
                              float* __restrict__ tapabc) {
    int idx = blockIdx.x * 256 + threadIdx.x;   // 4800
    if (idx >= 4800) return;
    int comp = idx % 3;
    int o = (idx / 3) & 63;
    int tap = idx / 192;
    const float* a = ABC + comp * 128;
    float s = 0.f;
    for (int i = 0; i < 128; ++i) s = fmaf(w1[(i * 64 + o) * 25 + tap], a[i], s);
    tapabc[idx] = s;
}

__global__ void clstab_kernel(const float* __restrict__ tapabc, const float* __restrict__ b1,
                              float* __restrict__ uvw) {
    int idx = blockIdx.x * 256 + threadIdx.x;   // 1600
    if (idx >= 1600) return;
    int o = idx & 63, cls = idx >> 6;
    int cy = cls / 5, cx = cls % 5;
    const int klo[5] = {2, 1, 0, 0, 0}, khi[5] = {4, 4, 4, 3, 2};
    const float inv31 = 1.f / 31.f;
    float u = b1[o], v = 0.f, w = 0.f;
    for (int ky = klo[cy]; ky <= khi[cy]; ++ky)
        for (int kx = klo[cx]; kx <= khi[cx]; ++kx) {
            int tap = (4 - ky) * 5 + (4 - kx);
            const float* t = &tapabc[(tap * 64 + o) * 3];
            u += t[0] + t[1] * (ky - 2) * inv31 + t[2] * (kx - 2) * inv31;
            v += t[1] * inv31;
            w += t[2] * inv31;
        }
    uvw[idx * 3] = u; uvw[idx * 3 + 1] = v; uvw[idx * 3 + 2] = w;
}

__global__ void pfill_kernel(const float* __restrict__ uvw, float* __restrict__ P) {
    int idx = blockIdx.x * 256 + threadIdx.x;   // 64*1024
    int o = idx >> 10, y = (idx >> 5) & 31, x = idx & 31;
    int cls = clsf(y) * 5 + clsf(x);
    const float* t = &uvw[(cls * 64 + o) * 3];
    P[idx] = t[0] + t[1] * y + t[2] * x;
}

// ---------------- latent collapse of convT1 ----------------

__global__ void wsum_kernel(const float* __restrict__ w1, float* __restrict__ Wsum) {
    int idx = blockIdx.x * 256 + threadIdx.x;
    if (idx >= 25 * 128 * 64) return;
    int cls = idx >> 13;
    int i = (idx >> 6) & 127;
    int o = idx & 63;
    int cy = cls / 5, cx = cls % 5;
    const int klo[5] = {2, 1, 0, 0, 0}, khi[5] = {4, 4, 4, 3, 2};
    float s = 0.f;
    for (int ky = klo[cy]; ky <= khi[cy]; ++ky)
        for (int kx = klo[cx]; kx <= khi[cx]; ++kx)
            s += w1[(i * 64 + o) * 25 + (4 - ky) * 5 + (4 - kx)];
    Wsum[idx] = s;
}

__global__ void m_kernel(const float* __restrict__ latent, const float* __restrict__ Wsum,
                         float* __restrict__ M) {
    int n = blockIdx.x, cls = blockIdx.y, o = threadIdx.x;
    const float* l = &latent[n * 128];
    const float* w = &Wsum[cls * 8192 + o];
    float a0 = 0.f, a1 = 0.f;
    for (int i = 0; i < 128; i += 2) {
        a0 = fmaf(l[i], w[i * 64], a0);
        a1 = fmaf(l[i + 1], w[(i + 1) * 64], a1);
    }
    M[(n * 25 + cls) * 64 + o] = a0 + a1;
}

// ---------------- weight prep ----------------

template<int I, int O>
__global__ void prep3_kernel(const float* __restrict__ w, short* __restrict__ wt) {
    constexpr int KS = I / 32;
    int idx = blockIdx.x * 256 + threadIdx.x;
    if (idx >= 9 * KS * 4 * O * 8) return;
    int j = idx & 7;
    int fi = idx >> 3;
    int o = fi % O;
    int g = (fi / O) & 3;
    int ks = (fi / (O * 4)) % KS;
    int t = fi / (O * 4 * KS);
    int i = ks * 32 + g * 8 + j;
    int ky = t / 3, kx = t % 3;
    wt[idx] = (short)f2bfu(w[(o * I + i) * 9 + ky * 3 + kx]);
}

__global__ void prepT2_kernel(const float* __restrict__ w2, short* __restrict__ wt) {
    int idx = blockIdx.x * 256 + threadIdx.x;
    if (idx >= 25 * 2 * 4 * 32 * 8) return;
    int j = idx & 7;
    int fi = idx >> 3;
    int o = fi & 31;
    int g = (fi >> 5) & 3;
    int ks = (fi >> 7) & 1;
    int t = fi >> 8;
    int i = ks * 32 + g * 8 + j;
    int ky = t / 5, kx = t % 5;
    wt[idx] = (short)f2bfu(w2[((i * 32 + o) * 5 + (4 - ky)) * 5 + (4 - kx)]);
}

// ---------------- MFMA implicit-GEMM 3x3 conv ----------------
// INBF/OUTBF: input/output stored as bf16 (numerically identical on conv
// paths since staging rounds to bf16 anyway).

template<int I, int O, int ACT, int INBF, int OUTBF>
__global__ __launch_bounds__(256) void mconv_kernel(
        const void* __restrict__ in_, const short* __restrict__ wt,
        const float* __restrict__ bias, void* __restrict__ out_) {
    constexpr int XC = 34, ROWS = 10, KS = I / 32, MF = O / 16, IH = I / 2;
    constexpr int ABUF = KS * 4 * O * 8;
    __shared__ short tile[ROWS * XC * I];
    __shared__ short ab[2 * ABUF];
    const int n = blockIdx.x, y0 = blockIdx.y * 8;
    const int tid = threadIdx.x, w = tid >> 6, l = tid & 63;

    for (int e = tid; e < ROWS * XC * IH; e += 256) {
        int cx = e % XC;
        int q = e / XC;
        int ip = q % IH;
        int r = q / IH;
        int gy = y0 - 1 + r, gx = cx - 1;
        unsigned int pack = 0u;
        if (gy >= 0 && gy < 32 && gx >= 0 && gx < 32) {
            if constexpr (INBF) {
                const unsigned short* p =
                    (const unsigned short*)in_ + (n * I + 2 * ip) * 1024 + gy * 32 + gx;
                pack = (unsigned int)p[0] | ((unsigned int)p[1024] << 16);
            } else {
                const float* p = (const float*)in_ + (n * I + 2 * ip) * 1024 + gy * 32 + gx;
                pack = cvt2(p[0], p[1024]);
            }
        }
        int off = ((r * XC + cx) * I + 2 * ip) * 2;
        off ^= (cx & 7) << 4;
        *(unsigned int*)((char*)tile + off) = pack;
    }
    for (int e = tid; e < ABUF / 8; e += 256)
        ((i32x4*)ab)[e] = ((const i32x4*)wt)[e];
    __syncthreads();

    const int lx = l & 15, lg = l >> 4;
    const int vlin = (lx * I + lg * 8) * 2;
    f32x4 acc[MF][4];
    #pragma unroll
    for (int m = 0; m < MF; ++m)
        #pragma unroll
        for (int f = 0; f < 4; ++f)
            acc[m][f] = (f32x4){0.f, 0.f, 0.f, 0.f};

    int ky = 0, kx = 0;
    #pragma unroll 1
    for (int t = 0; t < 9; ++t) {
        if (t + 1 < 9) {
            const i32x4* src = (const i32x4*)(wt + (t + 1) * ABUF);
            i32x4* dst = (i32x4*)(ab + ((t + 1) & 1) * ABUF);
            for (int e = tid; e < ABUF / 8; e += 256) dst[e] = src[e];
        }
        const short* al = ab + (t & 1) * ABUF;
        short8 af[KS][MF];
        #pragma unroll
        for (int ks = 0; ks < KS; ++ks)
            #pragma unroll
            for (int m = 0; m < MF; ++m)
                af[ks][m] = *(const short8*)(al + ((ks * 4 + lg) * O + m * 16 + lx) * 8);
        const int vkey = ((kx + lx) & 7) << 4;
        const int tv = ((2 * w + ky) * XC + kx) * I * 2 + vlin;
        #pragma unroll
        for (int ks = 0; ks < KS; ++ks) {
            short8 bf[4];
            #pragma unroll
            for (int f = 0; f < 4; ++f) {
                const int C = (((f >> 1) * XC + (f & 1) * 16) * I) * 2 + ks * 64;
                bf[f] = *(const short8*)((char*)tile + ((tv + C) ^ vkey));
            }
            #pragma unroll
            for (int m = 0; m < MF; ++m)
                #pragma unroll
                for (int f = 0; f < 4; ++f)
                    acc[m][f] = __builtin_amdgcn_mfma_f32_16x16x32_bf16(
                        af[ks][m], bf[f], acc[m][f], 0, 0, 0);
        }
        ++kx; if (kx == 3) { kx = 0; ++ky; }
        __syncthreads();
    }

    #pragma unroll
    for (int m = 0; m < MF; ++m) {
        #pragma unroll
        for (int f = 0; f < 4; ++f) {
            int yl = 2 * w + (f >> 1), x = (f & 1) * 16 + lx;
            #pragma unroll
            for (int r = 0; r < 4; ++r) {
                int och = m * 16 + lg * 4 + r;
                float v = acc[m][f][r] + bias[och];
                if (ACT == 1) v = v / (1.f + expf(-v));
                int oidx = (n * O + och) * 1024 + (y0 + yl) * 32 + x;
                if constexpr (OUTBF)
                    ((unsigned short*)out_)[oidx] = (unsigned short)f2bfu(v);
                else
                    ((float*)out_)[oidx] = v;
            }
        }
    }
}

// ---------------- convT2 via MFMA ----------------

__global__ __launch_bounds__(256) void convt2_mfma_kernel(
        const float* __restrict__ M, const float* __restrict__ P,
        const short* __restrict__ wt, const float* __restrict__ b2,
        float* __restrict__ feat) {
    constexpr int I = 64, O = 32, XC = 36, ROWS = 12, KS = 2, MF = 2;
    constexpr int ABUF = KS * 4 * O * 8;
    __shared__ short tile[ROWS * XC * I];
    __shared__ short ab[2 * ABUF];
    float* Ml = (float*)ab;
    const int n = blockIdx.x, y0 = blockIdx.y * 8;
    const int tid = threadIdx.x, w = tid >> 6, l = tid & 63;

    for (int e = tid; e < 1600; e += 256) Ml[e] = M[n * 1600 + e];
    __syncthreads();
    for (int e = tid; e < ROWS * XC * 32; e += 256) {
        int cx = e % XC;
        int q = e / XC;
        int ip = q & 31;
        int r = q >> 5;
        int gy = y0 - 2 + r, gx = cx - 2;
        float v0 = 0.f, v1 = 0.f;
        if (gy >= 0 && gy < 32 && gx >= 0 && gx < 32) {
            int cls = clsf(gy) * 5 + clsf(gx);
            int pp = gy * 32 + gx;
            v0 = fmaxf(Ml[cls * 64 + 2 * ip]     + P[((2 * ip) << 10) + pp], 0.f);
            v1 = fmaxf(Ml[cls * 64 + 2 * ip + 1] + P[((2 * ip + 1) << 10) + pp], 0.f);
        }
        int off = ((r * XC + cx) * I + 2 * ip) * 2;
        off ^= (cx & 7) << 4;
        *(unsigned int*)((char*)tile + off) = cvt2(v0, v1);
    }
    __syncthreads();
    for (int e = tid; e < ABUF / 8; e += 256)
        ((i32x4*)ab)[e] = ((const i32x4*)wt)[e];
    __syncthreads();

    const int lx = l & 15, lg = l >> 4;
    const int vlin = (lx * I + lg * 8) * 2;
    f32x4 acc[MF][4];
    #pragma unroll
    for (int m = 0; m < MF; ++m)
        #pragma unroll
        for (int f = 0; f < 4; ++f)
            acc[m][f] = (f32x4){0.f, 0.f, 0.f, 0.f};

    int ky = 0, kx = 0;
    #pragma unroll 1
    for (int t = 0; t < 25; ++t) {
        if (t + 1 < 25) {
            const i32x4* src = (const i32x4*)(wt + (t + 1) * ABUF);
            i32x4* dst = (i32x4*)(ab + ((t + 1) & 1) * ABUF);
            for (int e = tid; e < ABUF / 8; e += 256) dst[e] = src[e];
        }
        const short* al = ab + (t & 1) * ABUF;
        short8 af[KS][MF];
        #pragma unroll
        for (int ks = 0; ks < KS; ++ks)
            #pragma unroll
            for (int m = 0; m < MF; ++m)
                af[ks][m] = *(const short8*)(al + ((ks * 4 + lg) * O + m * 16 + lx) * 8);
        const int vkey = ((kx + lx) & 7) << 4;
        const int tv = ((2 * w + ky) * XC + kx) * I * 2 + vlin;
        #pragma unroll
        for (int ks = 0; ks < KS; ++ks) {
            short8 bf[4];
            #pragma unroll
            for (int f = 0; f < 4; ++f) {
                const int C = (((f >> 1) * XC + (f & 1) * 16) * I) * 2 + ks * 64;
                bf[f] = *(const short8*)((char*)tile + ((tv + C) ^ vkey));
            }
            #pragma unroll
            for (int m = 0; m < MF; ++m)
                #pragma unroll
                for (int f = 0; f < 4; ++f)
                    acc[m][f] = __builtin_amdgcn_mfma_f32_16x16x32_bf16(
                        af[ks][m], bf[f], acc[m][f], 0, 0, 0);
        }
        ++kx; if (kx == 5) { kx = 0; ++ky; }
        __syncthreads();
    }

    #pragma unroll
    for (int m = 0; m < MF; ++m) {
        #pragma unroll
        for (int f = 0; f < 4; ++f) {
            int yl = 2 * w + (f >> 1), x = (f & 1) * 16 + lx;
            #pragma unroll
            for (int r = 0; r < 4; ++r) {
                int och = m * 16 + lg * 4 + r;
                float v = fmaxf(acc[m][f][r] + b2[och], 0.f);
                feat[(n * O + och) * 1024 + (y0 + yl) * 32 + x] = v;
            }
        }
    }
}

// ---------------- a2 head: channel-dot (pass1) + tap-sum+softmax (pass2) ----------------
// s9[tap][n*1024+p] = sum_i a1out[n][i][p] * a2w[i][tap]

__global__ void a2dot_kernel(const unsigned short* __restrict__ in, const float* __restrict__ w,
                             float* __restrict__ s9) {
    __shared__ float wl[576];
    int t = threadIdx.x;
    for (int e = t; e < 576; e += 256) wl[e] = w[e];
    __syncthreads();
    int p = blockIdx.x * 256 + t;        // 262144 total
    int n = p >> 10, yx = p & 1023;
    float acc[9];
    #pragma unroll
    for (int k = 0; k < 9; ++k) acc[k] = 0.f;
    const unsigned short* ip = in + n * 65536 + yx;
    for (int i = 0; i < 64; ++i) {
        float v = bf2f(ip[i * 1024]);
        #pragma unroll
        for (int k = 0; k < 9; ++k) acc[k] = fmaf(v, wl[i * 9 + k], acc[k]);
    }
    #pragma unroll
    for (int k = 0; k < 9; ++k) s9[(k << 18) + p] = acc[k];
}

__global__ void a2soft_kernel(const float* __restrict__ s9, const float* __restrict__ b2,
                              float* __restrict__ outp) {
    int idx = blockIdx.x * 256 + threadIdx.x;  // 32768
    if (idx >= 32 * 1024) return;
    int bb = idx >> 10, yx = idx & 1023;
    int y = yx >> 5, x = yx & 31;
    float v[8];
    float bias = b2[0];
    #pragma unroll
    for (int s = 0; s < 8; ++s) {
        int n = bb * 8 + s;
        float a = bias;
        #pragma unroll
        for (int ky = 0; ky < 3; ++ky) {
            int yy = y + ky - 1;
            if (yy < 0 || yy > 31) continue;
            #pragma unroll
            for (int kx = 0; kx < 3; ++kx) {
                int xx = x + kx - 1;
                if (xx < 0 || xx > 31) continue;
                a += s9[((ky * 3 + kx) << 18) + (n << 10) + yy * 32 + xx];
            }
        }
        v[s] = a;
    }
    float m = -3.4e38f;
    #pragma unroll
    for (int s = 0; s < 8; ++s) m = fmaxf(m, v[s]);
    float sum = 0.f;
    #pragma unroll
    for (int s = 0; s < 8; ++s) { v[s] = expf(v[s] - m); sum += v[s]; }
    float inv = 1.f / sum;
    #pragma unroll
    for (int s = 0; s < 8; ++s) outp[AOFF + ((bb * 8 + s) << 10) + yx] = v[s] * inv;
}

// ---------------- VQ (writes bf16 q) ----------------

__global__ void vq_kernel(const float* __restrict__ feat, const float* __restrict__ codebook,
                          unsigned short* __restrict__ qfeat, float* __restrict__ partial) {
    __shared__ float cb[4096];
    __shared__ float cn[128];
    __shared__ float wsumr[4];
    int t = threadIdx.x;
    for (int e = t; e < 4096; e += 256) cb[e] = codebook[e];
    __syncthreads();
    if (t < 128) {
        float s = 0.f;
        #pragma unroll
        for (int c = 0; c < 32; ++c) { float v = cb[t * 32 + c]; s = fmaf(v, v, s); }
        cn[t] = s;
    }
    __syncthreads();
    int idx = blockIdx.x * 256 + t;
    int n = idx >> 10, yx = idx & 1023;
    float f[32];
    #pragma unroll
    for (int c = 0; c < 32; ++c) f[c] = feat[(n * 32 + c) * 1024 + yx];
    float best = 3.4e38f; int bi = 0;
    for (int k = 0; k < 128; ++k) {
        const float* cp = &cb[k * 32];
        float d0 = 0.f, d1 = 0.f, d2 = 0.f, d3 = 0.f;
        #pragma unroll
        for (int c = 0; c < 32; c += 4) {
            d0 = fmaf(f[c], cp[c], d0);
            d1 = fmaf(f[c + 1], cp[c + 1], d1);
            d2 = fmaf(f[c + 2], cp[c + 2], d2);
            d3 = fmaf(f[c + 3], cp[c + 3], d3);
        }
        float d = cn[k] - 2.f * ((d0 + d1) + (d2 + d3));
        if (d < best) { best = d; bi = k; }
    }
    float l = 0.f;
    const float* q = &cb[bi * 32];
    #pragma unroll
    for (int c = 0; c < 32; ++c) {
        float qv = q[c];
        qfeat[(n * 32 + c) * 1024 + yx] = (unsigned short)f2bfu(qv);
        float dd = qv - f[c];
        l = fmaf(dd, dd, l);
    }
    for (int off = 32; off > 0; off >>= 1) l += __shfl_down(l, off);
    int lane = t & 63, wid = t >> 6;
    if (lane == 0) wsumr[wid] = l;
    __syncthreads();
    if (t == 0) partial[blockIdx.x] = (wsumr[0] + wsumr[1]) + (wsumr[2] + wsumr[3]);
}

__global__ void recon_kernel(const unsigned short* __restrict__ colors, float* __restrict__ outp) {
    int idx = blockIdx.x * 256 + threadIdx.x;
    int yx = idx & 1023;
    int v = (idx >> 10) & 63;
    int bb = idx >> 16;
    float acc = 0.f;
    #pragma unroll
    for (int s = 0; s < 8; ++s) {
        float a = outp[AOFF + ((bb * 8 + s) << 10) + yx];
        float c = bf2f(colors[((bb * 8 + s) * 64 + v) * 1024 + yx]);
        acc = fmaf(a, c, acc);
    }
    outp[idx] = acc;
}

__global__ void loss_kernel(const float* __restrict__ partial, float* __restrict__ outp) {
    __shared__ float red[4];
    int t = threadIdx.x;
    float s = 0.f;
    for (int i = t; i < 1024; i += 256) s += partial[i];
    for (int o = 32; o > 0; o >>= 1) s += __shfl_down(s, o);
    if ((t & 63) == 0) red[t >> 6] = s;
    __syncthreads();
    if (t == 0) outp[LOFF] = 1.25f * ((red[0] + red[1]) + (red[2] + red[3])) / 8388608.0f;
}

extern "C" void kernel_launch(void* const* d_in, const int* in_sizes, int n_in,
                              void* d_out, int out_size, void* d_ws, size_t ws_size,
                              hipStream_t stream) {
    const float* latent  = (const float*)d_in[0];
    const float* pos_w   = (const float*)d_in[1];
    const float* pos_b   = (const float*)d_in[2];
    const float* ct1_w   = (const float*)d_in[3];
    const float* ct1_b   = (const float*)d_in[4];
    const float* ct2_w   = (const float*)d_in[5];
    const float* ct2_b   = (const float*)d_in[6];
    const float* codebook= (const float*)d_in[7];
    const float* c1_w    = (const float*)d_in[8];
    const float* c1_b    = (const float*)d_in[9];
    const float* c2_w    = (const float*)d_in[10];
    const float* c2_b    = (const float*)d_in[11];
    const float* a1_w    = (const float*)d_in[12];
    const float* a1_b    = (const float*)d_in[13];
    const float* a2_w    = (const float*)d_in[14];
    const float* a2_b    = (const float*)d_in[15];
    float* out = (float*)d_out;

    float* ws     = (float*)d_ws;
    float* feat   = ws;                      // 8388608 floats (fp32: vq needs precision)
    float* s9     = feat + 8388608;          // 2359296
    float* ABC    = s9 + 2359296;            // 384
    float* tapabc = ABC + 384;               // 4800
    float* uvw    = tapabc + 4800;           // 4800
    float* P      = uvw + 4800;              // 65536
    float* Wsum   = P + 65536;               // 204800
    float* M      = Wsum + 204800;           // 409600
    float* partial= M + 409600;              // 1024
    short* wtA    = (short*)(partial + 1024);    // 18432 shorts
    short* wtC1   = wtA + 18432;                 // 18432
    short* wtC2   = wtC1 + 18432;                // 36864
    short* wtT2   = wtC2 + 36864;                // 51200
    unsigned short* tmpb    = (unsigned short*)(wtT2 + 51200);  // 16777216 shorts (bf16)
    unsigned short* qfeatb  = tmpb + 16777216;                  // 8388608 shorts
    unsigned short* colorsb = qfeatb + 8388608;                 // 16777216 shorts

    abc_kernel<<<1, 128, 0, stream>>>(pos_w, pos_b, ABC);
    tapdot_kernel<<<19, 256, 0, stream>>>(ct1_w, ABC, tapabc);
    clstab_kernel<<<7, 256, 0, stream>>>(tapabc, ct1_b, uvw);
    pfill_kernel<<<256, 256, 0, stream>>>(uvw, P);
    wsum_kernel<<<800, 256, 0, stream>>>(ct1_w, Wsum);
    m_kernel<<<dim3(256, 25), 64, 0, stream>>>(latent, Wsum, M);
    prep3_kernel<32, 64><<<72, 256, 0, stream>>>(a1_w, wtA);
    prep3_kernel<32, 64><<<72, 256, 0, stream>>>(c1_w, wtC1);
    prep3_kernel<64, 64><<<144, 256, 0, stream>>>(c2_w, wtC2);
    prepT2_kernel<<<200, 256, 0, stream>>>(ct2_w, wtT2);

    convt2_mfma_kernel<<<dim3(256, 4), 256, 0, stream>>>(M, P, wtT2, ct2_b, feat);
    // alpha head: a1 (fp32 in, bf16 out) -> channel-dot -> tap-sum+softmax
    mconv_kernel<32, 64, 1, 0, 1><<<dim3(256, 4), 256, 0, stream>>>(feat, wtA, a1_b, tmpb);
    a2dot_kernel<<<1024, 256, 0, stream>>>(tmpb, a2_w, s9);
    a2soft_kernel<<<128, 256, 0, stream>>>(s9, a2_b, out);
    // VQ
    vq_kernel<<<1024, 256, 0, stream>>>(feat, codebook, qfeatb, partial);
    // color head (bf16 end to end)
    mconv_kernel<32, 64, 1, 1, 1><<<dim3(256, 4), 256, 0, stream>>>(qfeatb, wtC1, c1_b, tmpb);
    mconv_kernel<64, 64, 0, 1, 1><<<dim3(256, 4), 256, 0, stream>>>(tmpb, wtC2, c2_b, colorsb);
    recon_kernel<<<8192, 256, 0, stream>>>(colorsb, out);
    loss_kernel<<<1, 256, 0, stream>>>(partial, out);
}